// Round 4
// baseline (360.415 us; speedup 1.0000x reference)
//
#include <hip/hip_runtime.h>
#include <math.h>

// SpatialProcessor: 2-layer GAT over top-K cosine-sim graph. All f32.
// R3 -> R4: sim_topk histogram/atomics ELIMINATED. New exact scheme:
//   pass1: per-thread per-row register running-max over disjoint j-subsets
//          (1 v_max per sim, zero LDS atomics)
//   select: per row, t = 20th-largest of the 512 subset maxima (wave argmax
//          rounds). Guarantee: >=20 subsets have max >= t, disjoint => 
//          count(sim>=t) >= 20 => top-20 subset of candidates. Typically M=20-22.
//   pass2: recompute bit-identical sims, collect {monokey(sim) >= t_mono},
//          exact u64-key rank-by-count. Overflow (M>CAP) -> exact fallback.

#define N_NODES 10000
#define EMB_D   16
#define IN_DIM  128
#define H1      4
#define CDIM    64
#define D1      256   // 4*64
#define K_TOP   20
#define NEIGH   21    // K_TOP + self loop
#define RPB     8     // rows per sim block
#define TPB     512
#define CAP     128   // candidate capacity per row (M>CAP -> exact fallback)

__device__ __forceinline__ unsigned monokey(float v) {
  unsigned u = __float_as_uint(v);
  return (u & 0x80000000u) ? ~u : (u | 0x80000000u);
}

// Fixed-order fmaf dot; MUST be bit-identical at every call site.
__device__ __forceinline__ float dot16q(float4 qa, float4 qb, float4 qc, float4 qd,
                                        float4 v0, float4 v1, float4 v2, float4 v3) {
  float a = 0.f;
  a = fmaf(qa.x, v0.x, a); a = fmaf(qa.y, v0.y, a);
  a = fmaf(qa.z, v0.z, a); a = fmaf(qa.w, v0.w, a);
  a = fmaf(qb.x, v1.x, a); a = fmaf(qb.y, v1.y, a);
  a = fmaf(qb.z, v1.z, a); a = fmaf(qb.w, v1.w, a);
  a = fmaf(qc.x, v2.x, a); a = fmaf(qc.y, v2.y, a);
  a = fmaf(qc.z, v2.z, a); a = fmaf(qc.w, v2.w, a);
  a = fmaf(qd.x, v3.x, a); a = fmaf(qd.y, v3.y, a);
  a = fmaf(qd.z, v3.z, a); a = fmaf(qd.w, v3.w, a);
  return a;
}

__global__ __launch_bounds__(256) void normalize_kernel(
    const float* __restrict__ emb, float* __restrict__ nrm) {
  int i = blockIdx.x * 256 + threadIdx.x;
  if (i >= N_NODES) return;
  const float4* p = (const float4*)(emb + (size_t)i * EMB_D);
  float4 v[4];
  float ss = 0.f;
#pragma unroll
  for (int k = 0; k < 4; k++) {
    v[k] = p[k];
    ss = fmaf(v[k].x, v[k].x, ss);
    ss = fmaf(v[k].y, v[k].y, ss);
    ss = fmaf(v[k].z, v[k].z, ss);
    ss = fmaf(v[k].w, v[k].w, ss);
  }
  float nv = sqrtf(ss);
  float4* o = (float4*)(nrm + (size_t)i * EMB_D);
#pragma unroll
  for (int k = 0; k < 4; k++) {
    float4 t;
    t.x = v[k].x / nv; t.y = v[k].y / nv; t.z = v[k].z / nv; t.w = v[k].w / nv;
    o[k] = t;
  }
}

// 8 rows per 512-thread block; grid = 1250.
__global__ __launch_bounds__(TPB) void sim_topk_kernel(
    const float* __restrict__ nrm, int* __restrict__ topk) {
  __shared__ float s_q[RPB][EMB_D];                // 512 B
  __shared__ float s_smax[RPB][TPB];               // 16 KB subset maxima
  __shared__ unsigned s_thr[RPB];                  // t per row (monokey space)
  __shared__ int s_cand[RPB][CAP];                 // 4 KB
  __shared__ unsigned long long s_ckey[RPB][CAP];  // 8 KB
  __shared__ int s_cnt[RPB];

  int tid = threadIdx.x;
  int row0 = blockIdx.x * RPB;

  if (tid < RPB * EMB_D) ((float*)s_q)[tid] = nrm[(size_t)row0 * EMB_D + tid];
  if (tid < RPB) s_cnt[tid] = 0;
  __syncthreads();

  // ---- Pass 1: per-thread per-row running max (no atomics, no histogram) ----
  float mx[RPB];
#pragma unroll
  for (int r = 0; r < RPB; r++) mx[r] = -INFINITY;

  for (int it = 0; it < 5; ++it) {
    int j0 = it * (TPB * 4) + tid * 4;   // 4 consecutive rows per thread
    if (j0 < N_NODES) {                  // 10000 % 4 == 0: all-or-none
      float4 v[4][4];
#pragma unroll
      for (int jj = 0; jj < 4; jj++) {
        const float4* pj = (const float4*)(nrm + (size_t)(j0 + jj) * EMB_D);
        v[jj][0] = pj[0]; v[jj][1] = pj[1]; v[jj][2] = pj[2]; v[jj][3] = pj[3];
      }
#pragma unroll
      for (int r = 0; r < RPB; r++) {
        const float4* qp = (const float4*)&s_q[r][0];
        float4 qa = qp[0], qb = qp[1], qc = qp[2], qd = qp[3];
#pragma unroll
        for (int jj = 0; jj < 4; jj++) {
          float sim = dot16q(qa, qb, qc, qd, v[jj][0], v[jj][1], v[jj][2], v[jj][3]);
          mx[r] = fmaxf(mx[r], sim);
        }
      }
    }
  }
#pragma unroll
  for (int r = 0; r < RPB; r++) s_smax[r][tid] = mx[r];
  __syncthreads();

  // ---- Threshold: wave w owns row w; t = 20th-largest of 512 subset maxima ----
  {
    int w = tid >> 6, lane = tid & 63;
    float vals[8];
#pragma unroll
    for (int k = 0; k < 8; k++) vals[k] = s_smax[w][k * 64 + lane];
    unsigned long long bk = 0ull;
    for (int round = 0; round < K_TOP; round++) {
      bk = 0ull;
#pragma unroll
      for (int k = 0; k < 8; k++) {
        unsigned long long key =
            ((unsigned long long)monokey(vals[k]) << 32) | (unsigned)(k * 64 + lane);
        if (key > bk) bk = key;
      }
#pragma unroll
      for (int off = 32; off > 0; off >>= 1) {
        unsigned long long o = __shfl_xor(bk, off);
        if (o > bk) bk = o;
      }
      int slot = (int)(bk & 0xFFFFFFFFull);
      if ((slot & 63) == lane) vals[slot >> 6] = -INFINITY;  // remove one instance
    }
    if (lane == 0) s_thr[w] = (unsigned)(bk >> 32);  // 20th-largest, monokey space
  }
  __syncthreads();

  // ---- Pass 2: collect candidates with monokey(sim) >= t (exact compare) ----
  for (int it = 0; it < 5; ++it) {
    int j0 = it * (TPB * 4) + tid * 4;
    if (j0 < N_NODES) {
      float4 v[4][4];
#pragma unroll
      for (int jj = 0; jj < 4; jj++) {
        const float4* pj = (const float4*)(nrm + (size_t)(j0 + jj) * EMB_D);
        v[jj][0] = pj[0]; v[jj][1] = pj[1]; v[jj][2] = pj[2]; v[jj][3] = pj[3];
      }
#pragma unroll
      for (int r = 0; r < RPB; r++) {
        unsigned thr = s_thr[r];
        const float4* qp = (const float4*)&s_q[r][0];
        float4 qa = qp[0], qb = qp[1], qc = qp[2], qd = qp[3];
#pragma unroll
        for (int jj = 0; jj < 4; jj++) {
          float sim = dot16q(qa, qb, qc, qd, v[jj][0], v[jj][1], v[jj][2], v[jj][3]);
          unsigned mk = monokey(sim);
          if (mk >= thr) {
            int slot = atomicAdd(&s_cnt[r], 1);
            if (slot < CAP) {
              s_cand[r][slot] = j0 + jj;
              s_ckey[r][slot] = ((unsigned long long)mk << 32) |
                                (unsigned long long)(0xFFFFFFFFu - (unsigned)(j0 + jj));
            }
          }
        }
      }
    }
  }
  __syncthreads();

  // ---- Rank-by-count (wave per row); exact fallback if M > CAP ----
  {
    int w = tid >> 6, lane = tid & 63;
    int row = row0 + w;
    int M = s_cnt[w];
    if (M <= CAP) {   // M >= 20 guaranteed by construction
      for (int c = lane; c < M; c += 64) {
        unsigned long long mykey = s_ckey[w][c];
        int rank = 0;
        for (int i = 0; i < M; i++) rank += (s_ckey[w][i] > mykey) ? 1 : 0;
        if (rank < K_TOP) topk[(size_t)row * K_TOP + rank] = s_cand[w][c];
      }
    } else {
      // Exact wave-local fallback: 20 rounds of argmax with decreasing key cap.
      const float4* qp = (const float4*)&s_q[w][0];
      float4 qa = qp[0], qb = qp[1], qc = qp[2], qd = qp[3];
      unsigned long long prev = ~0ull;
      for (int r = 0; r < K_TOP; r++) {
        unsigned long long best = 0ull;
        for (int j = lane; j < N_NODES; j += 64) {
          const float4* pj = (const float4*)(nrm + (size_t)j * EMB_D);
          float sim = dot16q(qa, qb, qc, qd, pj[0], pj[1], pj[2], pj[3]);
          unsigned long long key = ((unsigned long long)monokey(sim) << 32) |
                                   (unsigned long long)(0xFFFFFFFFu - (unsigned)j);
          if (key < prev && key > best) best = key;
        }
#pragma unroll
        for (int off = 32; off > 0; off >>= 1) {
          unsigned long long o = __shfl_down(best, off);
          if (o > best) best = o;
        }
        best = __shfl(best, 0);
        prev = best;
        if (lane == 0)
          topk[(size_t)row * K_TOP + r] =
              (int)(0xFFFFFFFFu - (unsigned)(best & 0xFFFFFFFFull));
      }
    }
  }
}

// C[10000,256] = A[10000,128] @ B[128,256]. 16 rows/block, blockDim (256,2).
__global__ __launch_bounds__(512) void gemm1_kernel(
    const float* __restrict__ A, const float* __restrict__ B, float* __restrict__ Cc) {
  __shared__ float As[16][IN_DIM];
  int r0 = blockIdx.x * 16;
  int tid = threadIdx.y * 256 + threadIdx.x;
  {
    int rr = tid >> 5;
    int kk = tid & 31;
    ((float4*)&As[rr][0])[kk] = ((const float4*)(A + (size_t)(r0 + rr) * IN_DIM))[kk];
  }
  __syncthreads();
  int col = threadIdx.x;
  int y = threadIdx.y;
  float acc[8] = {0, 0, 0, 0, 0, 0, 0, 0};
#pragma unroll 4
  for (int k = 0; k < IN_DIM; k++) {
    float bv = B[(size_t)k * D1 + col];
#pragma unroll
    for (int r = 0; r < 8; r++) acc[r] = fmaf(As[y * 8 + r][k], bv, acc[r]);
  }
#pragma unroll
  for (int r = 0; r < 8; r++)
    Cc[(size_t)(r0 + y * 8 + r) * D1 + col] = acc[r];
}

// C[10000,64] = A[10000,256] @ B[256,64]. 16 rows/block, blockDim (64,4).
__global__ __launch_bounds__(256) void gemm2_kernel(
    const float* __restrict__ A, const float* __restrict__ B, float* __restrict__ Cc) {
  __shared__ float As[16][D1];
  int r0 = blockIdx.x * 16;
  int tid = threadIdx.y * 64 + threadIdx.x;
  for (int e = tid; e < 16 * (D1 / 4); e += 256) {
    int rr = e >> 6;
    int kk = e & 63;
    ((float4*)&As[rr][0])[kk] = ((const float4*)(A + (size_t)(r0 + rr) * D1))[kk];
  }
  __syncthreads();
  int col = threadIdx.x;
  int y = threadIdx.y;
  float acc[4] = {0, 0, 0, 0};
#pragma unroll 4
  for (int k = 0; k < D1; k++) {
    float bv = B[(size_t)k * CDIM + col];
#pragma unroll
    for (int r = 0; r < 4; r++) acc[r] = fmaf(As[y * 4 + r][k], bv, acc[r]);
  }
#pragma unroll
  for (int r = 0; r < 4; r++)
    Cc[(size_t)(r0 + y * 4 + r) * CDIM + col] = acc[r];
}

__global__ __launch_bounds__(256) void e1_kernel(
    const float* __restrict__ h1p, const float* __restrict__ a_src,
    const float* __restrict__ a_tgt, float* __restrict__ es, float* __restrict__ et) {
  int n = blockIdx.x;
  int tid = threadIdx.x;
  int w = tid >> 6, c = tid & 63;
  float hv = h1p[(size_t)n * D1 + tid];
  float ps = hv * a_src[tid];
  float pt = hv * a_tgt[tid];
#pragma unroll
  for (int off = 32; off > 0; off >>= 1) {
    ps += __shfl_down(ps, off);
    pt += __shfl_down(pt, off);
  }
  if (c == 0) {
    es[(size_t)n * H1 + w] = ps;
    et[(size_t)n * H1 + w] = pt;
  }
}

__global__ __launch_bounds__(256) void agg1_kernel(
    const float* __restrict__ h1p, const float* __restrict__ es,
    const float* __restrict__ et, const int* __restrict__ topk,
    const float* __restrict__ b1, float* __restrict__ h1o) {
  int i = blockIdx.x;
  int tid = threadIdx.x;
  __shared__ int nb[NEIGH];
  __shared__ float lg[NEIGH][H1];
  if (tid < K_TOP) nb[tid] = topk[(size_t)i * K_TOP + tid];
  else if (tid == K_TOP) nb[K_TOP] = i;
  __syncthreads();
  if (tid < NEIGH * H1) {
    int e = tid & 3, jj = tid >> 2;
    float L = es[(size_t)i * H1 + e] + et[(size_t)nb[jj] * H1 + e];
    lg[jj][e] = (L > 0.f) ? L : 0.2f * L;
  }
  __syncthreads();
  int h = tid >> 6;
  float m = -INFINITY;
#pragma unroll
  for (int jj = 0; jj < NEIGH; jj++) m = fmaxf(m, lg[jj][h]);
  float z = 0.f, acc = 0.f;
#pragma unroll
  for (int jj = 0; jj < NEIGH; jj++) {
    float w = expf(lg[jj][h] - m);
    z += w;
    acc = fmaf(w, h1p[(size_t)nb[jj] * D1 + tid], acc);
  }
  float o = acc / z + b1[tid];
  h1o[(size_t)i * D1 + tid] = fmaxf(o, 0.f);
}

__global__ __launch_bounds__(256) void e2_kernel(
    const float* __restrict__ h2p, const float* __restrict__ a_src,
    const float* __restrict__ a_tgt, float* __restrict__ es, float* __restrict__ et) {
  int tid = threadIdx.x;
  int n = blockIdx.x * 4 + (tid >> 6);
  int c = tid & 63;
  float hv = h2p[(size_t)n * CDIM + c];
  float ps = hv * a_src[c];
  float pt = hv * a_tgt[c];
#pragma unroll
  for (int off = 32; off > 0; off >>= 1) {
    ps += __shfl_down(ps, off);
    pt += __shfl_down(pt, off);
  }
  if (c == 0) { es[n] = ps; et[n] = pt; }
}

__global__ __launch_bounds__(256) void agg2_kernel(
    const float* __restrict__ h2p, const float* __restrict__ es,
    const float* __restrict__ et, const int* __restrict__ topk,
    const float* __restrict__ b2, float* __restrict__ out) {
  int tid = threadIdx.x;
  int li = tid >> 6;
  int c = tid & 63;
  int i = blockIdx.x * 4 + li;
  __shared__ int nb[4][NEIGH];
  __shared__ float lg[4][NEIGH];
  if (tid < 4 * NEIGH) {
    int li2 = tid / NEIGH, jj = tid % NEIGH;
    int node = blockIdx.x * 4 + li2;
    nb[li2][jj] = (jj < K_TOP) ? topk[(size_t)node * K_TOP + jj] : node;
  }
  __syncthreads();
  if (tid < 4 * NEIGH) {
    int li2 = tid / NEIGH, jj = tid % NEIGH;
    int node = blockIdx.x * 4 + li2;
    float L = es[node] + et[nb[li2][jj]];
    lg[li2][jj] = (L > 0.f) ? L : 0.2f * L;
  }
  __syncthreads();
  float m = -INFINITY;
#pragma unroll
  for (int jj = 0; jj < NEIGH; jj++) m = fmaxf(m, lg[li][jj]);
  float z = 0.f, acc = 0.f;
#pragma unroll
  for (int jj = 0; jj < NEIGH; jj++) {
    float w = expf(lg[li][jj] - m);
    z += w;
    acc = fmaf(w, h2p[(size_t)nb[li][jj] * CDIM + c], acc);
  }
  out[(size_t)i * CDIM + c] = acc / z + b2[c];
}

extern "C" void kernel_launch(void* const* d_in, const int* in_sizes, int n_in,
                              void* d_out, int out_size, void* d_ws, size_t ws_size,
                              hipStream_t stream) {
  const float* x   = (const float*)d_in[0];
  const float* emb = (const float*)d_in[1];
  const float* W1  = (const float*)d_in[2];
  const float* a1s = (const float*)d_in[3];
  const float* a1t = (const float*)d_in[4];
  const float* b1  = (const float*)d_in[5];
  const float* W2  = (const float*)d_in[6];
  const float* a2s = (const float*)d_in[7];
  const float* a2t = (const float*)d_in[8];
  const float* b2  = (const float*)d_in[9];
  float* out = (float*)d_out;

  size_t off = 0;
  auto alloc = [&](size_t bytes) {
    void* p = (char*)d_ws + off;
    off += (bytes + 255) & ~(size_t)255;
    return p;
  };
  float* nrm  = (float*)alloc((size_t)N_NODES * EMB_D * sizeof(float));
  int*   topk = (int*)  alloc((size_t)N_NODES * K_TOP * sizeof(int));
  float* h1p  = (float*)alloc((size_t)N_NODES * D1 * sizeof(float));
  float* e1s  = (float*)alloc((size_t)N_NODES * H1 * sizeof(float));
  float* e1t  = (float*)alloc((size_t)N_NODES * H1 * sizeof(float));
  float* h1   = (float*)alloc((size_t)N_NODES * D1 * sizeof(float));
  float* h2p  = (float*)alloc((size_t)N_NODES * CDIM * sizeof(float));
  float* e2s  = (float*)alloc((size_t)N_NODES * sizeof(float));
  float* e2t  = (float*)alloc((size_t)N_NODES * sizeof(float));
  (void)ws_size; (void)in_sizes; (void)n_in; (void)out_size;

  normalize_kernel<<<(N_NODES + 255) / 256, 256, 0, stream>>>(emb, nrm);
  sim_topk_kernel<<<N_NODES / RPB, TPB, 0, stream>>>(nrm, topk);
  gemm1_kernel<<<N_NODES / 16, dim3(256, 2), 0, stream>>>(x, W1, h1p);
  e1_kernel<<<N_NODES, 256, 0, stream>>>(h1p, a1s, a1t, e1s, e1t);
  agg1_kernel<<<N_NODES, 256, 0, stream>>>(h1p, e1s, e1t, topk, b1, h1);
  gemm2_kernel<<<N_NODES / 16, dim3(64, 4), 0, stream>>>(h1, W2, h2p);
  e2_kernel<<<N_NODES / 4, 256, 0, stream>>>(h2p, a2s, a2t, e2s, e2t);
  agg2_kernel<<<N_NODES / 4, 256, 0, stream>>>(h2p, e2s, e2t, topk, b2, out);
}

// Round 5
// 220.269 us; speedup vs baseline: 1.6363x; 1.6363x over previous
//
#include <hip/hip_runtime.h>
#include <math.h>

// SpatialProcessor: 2-layer GAT over top-K cosine-sim graph. All f32.
// R4 -> R5: sim_topk moved to the MATRIX pipe. bf16 MFMA (32x32x16, K=16
// exact fit) computes approx sims (|err| <= 2^-7); per-row threshold from
// 256 disjoint subset-maxima (20th-largest, guard 2eps=0.016); pass2 MFMA
// rescan collects ~25-35 candidates/row; exact f32 fmaf dot + rank-by-count
// gives bit-exact (sim desc, idx asc) top-20. Fallback: exact wave argmax.

#define N_NODES 10000
#define EMB_D   16
#define IN_DIM  128
#define H1      4
#define CDIM    64
#define D1      256   // 4*64
#define K_TOP   20
#define NEIGH   21    // K_TOP + self loop
#define SROWS   32    // rows per sim block
#define NTILES  313   // ceil(10000/32)
#define CAPM    96    // candidate capacity per row
#define GUARD   0.016f // 2 * bf16 dot error bound (2^-7)

typedef __attribute__((ext_vector_type(8)))  short short8;   // 8 bf16
typedef __attribute__((ext_vector_type(16))) float f32x16;

__device__ __forceinline__ unsigned monokey(float v) {
  unsigned u = __float_as_uint(v);
  return (u & 0x80000000u) ? ~u : (u | 0x80000000u);
}
__device__ __forceinline__ float invmono(unsigned m) {
  unsigned u = (m & 0x80000000u) ? (m ^ 0x80000000u) : ~m;
  return __uint_as_float(u);
}
__device__ __forceinline__ unsigned short f32_to_bf16(float f) {
  unsigned u = __float_as_uint(f);
  unsigned r = 0x7FFFu + ((u >> 16) & 1u);
  return (unsigned short)((u + r) >> 16);
}

// Fixed-order fmaf dot; MUST be bit-identical at every call site.
__device__ __forceinline__ float dot16q(float4 qa, float4 qb, float4 qc, float4 qd,
                                        float4 v0, float4 v1, float4 v2, float4 v3) {
  float a = 0.f;
  a = fmaf(qa.x, v0.x, a); a = fmaf(qa.y, v0.y, a);
  a = fmaf(qa.z, v0.z, a); a = fmaf(qa.w, v0.w, a);
  a = fmaf(qb.x, v1.x, a); a = fmaf(qb.y, v1.y, a);
  a = fmaf(qb.z, v1.z, a); a = fmaf(qb.w, v1.w, a);
  a = fmaf(qc.x, v2.x, a); a = fmaf(qc.y, v2.y, a);
  a = fmaf(qc.z, v2.z, a); a = fmaf(qc.w, v2.w, a);
  a = fmaf(qd.x, v3.x, a); a = fmaf(qd.y, v3.y, a);
  a = fmaf(qd.z, v3.z, a); a = fmaf(qd.w, v3.w, a);
  return a;
}

__global__ __launch_bounds__(256) void normalize_kernel(
    const float* __restrict__ emb, float* __restrict__ nrm,
    unsigned short* __restrict__ nrmh) {
  int i = blockIdx.x * 256 + threadIdx.x;
  if (i >= N_NODES) return;
  const float4* p = (const float4*)(emb + (size_t)i * EMB_D);
  float4 v[4];
  float ss = 0.f;
#pragma unroll
  for (int k = 0; k < 4; k++) {
    v[k] = p[k];
    ss = fmaf(v[k].x, v[k].x, ss);
    ss = fmaf(v[k].y, v[k].y, ss);
    ss = fmaf(v[k].z, v[k].z, ss);
    ss = fmaf(v[k].w, v[k].w, ss);
  }
  float nv = sqrtf(ss);
  float4* o = (float4*)(nrm + (size_t)i * EMB_D);
  ushort4* oh = (ushort4*)(nrmh + (size_t)i * EMB_D);
#pragma unroll
  for (int k = 0; k < 4; k++) {
    float4 t;
    t.x = v[k].x / nv; t.y = v[k].y / nv; t.z = v[k].z / nv; t.w = v[k].w / nv;
    o[k] = t;
    ushort4 h;
    h.x = f32_to_bf16(t.x); h.y = f32_to_bf16(t.y);
    h.z = f32_to_bf16(t.z); h.w = f32_to_bf16(t.w);
    oh[k] = h;
  }
}

// 32 rows per 512-thread block (8 waves split the 313 j-tiles); grid 313.
__global__ __launch_bounds__(512) void sim_topk_kernel(
    const float* __restrict__ nrm, const unsigned short* __restrict__ nrmh,
    int* __restrict__ topk) {
  __shared__ unsigned short s_qbf[SROWS * EMB_D];        // 1 KB
  __shared__ float s_qf[SROWS * EMB_D];                  // 2 KB
  __shared__ float s_smax[SROWS][256];                   // 32 KB
  __shared__ float s_thr[SROWS];
  __shared__ unsigned long long s_ckey[SROWS][CAPM];     // 24 KB
  __shared__ int s_cnt[SROWS];

  int tid = threadIdx.x;
  int w = tid >> 6, lane = tid & 63;
  int row0 = blockIdx.x * SROWS;

  if (tid < SROWS * EMB_D) {
    int gi = row0 * EMB_D + tid;
    float v = (gi < N_NODES * EMB_D) ? nrm[gi] : 0.f;
    s_qf[tid] = v;
    s_qbf[tid] = f32_to_bf16(v);
  }
  if (tid < SROWS) s_cnt[tid] = 0;
  __syncthreads();

  // A-frag (identical across waves): lane -> row (lane&31), dims (lane>>5)*8..+7
  short8 afrag = *(const short8*)&s_qbf[(lane & 31) * EMB_D + (lane >> 5) * 8];
  const f32x16 zacc = (f32x16)0.0f;

  // ---- Pass 1: MFMA approx sims; per-lane per-reg running max ----
  float rm[16];
#pragma unroll
  for (int r = 0; r < 16; r++) rm[r] = -INFINITY;

  for (int t = w; t < NTILES; t += 8) {
    int node = t * 32 + (lane & 31);
    short8 bfrag = (short8)(short)0;
    if (node < N_NODES)
      bfrag = *(const short8*)&nrmh[(size_t)node * EMB_D + (lane >> 5) * 8];
    f32x16 acc = __builtin_amdgcn_mfma_f32_32x32x16_bf16(afrag, bfrag, zacc, 0, 0, 0);
    if (node < N_NODES) {
#pragma unroll
      for (int r = 0; r < 16; r++) rm[r] = fmaxf(rm[r], acc[r]);
    }
  }
#pragma unroll
  for (int r = 0; r < 16; r++) {
    int rl = (r & 3) + 8 * (r >> 2) + 4 * (lane >> 5);   // C-layout row
    s_smax[rl][w * 32 + (lane & 31)] = rm[r];
  }
  __syncthreads();

  // ---- Threshold: wave w rows 4w..4w+3; t = 20th-largest of 256 subset maxima
  for (int q = 0; q < 4; q++) {
    int row = w * 4 + q;
    float vals[4];
#pragma unroll
    for (int k = 0; k < 4; k++) vals[k] = s_smax[row][k * 64 + lane];
    unsigned long long bk = 0ull;
    for (int round = 0; round < K_TOP; round++) {
      bk = 0ull;
#pragma unroll
      for (int k = 0; k < 4; k++) {
        unsigned long long key =
            ((unsigned long long)monokey(vals[k]) << 32) | (unsigned)(k * 64 + lane);
        if (key > bk) bk = key;
      }
#pragma unroll
      for (int off = 32; off > 0; off >>= 1) {
        unsigned long long o = __shfl_xor(bk, off);
        if (o > bk) bk = o;
      }
      int slot = (int)(bk & 0xFFFFFFFFull);
      if ((slot & 63) == lane) vals[slot >> 6] = -INFINITY;
    }
    if (lane == 0)
      s_thr[row] = (row0 + row < N_NODES)
                       ? invmono((unsigned)(bk >> 32)) - GUARD
                       : INFINITY;   // fake rows: no candidates
  }
  __syncthreads();

  // Hoist per-(lane,reg) thresholds into registers.
  float thr_r[16];
#pragma unroll
  for (int r = 0; r < 16; r++)
    thr_r[r] = s_thr[(r & 3) + 8 * (r >> 2) + 4 * (lane >> 5)];

  // ---- Pass 2: MFMA rescan; candidates get exact f32 dot + key append ----
  for (int t = w; t < NTILES; t += 8) {
    int node = t * 32 + (lane & 31);
    short8 bfrag = (short8)(short)0;
    if (node < N_NODES)
      bfrag = *(const short8*)&nrmh[(size_t)node * EMB_D + (lane >> 5) * 8];
    f32x16 acc = __builtin_amdgcn_mfma_f32_32x32x16_bf16(afrag, bfrag, zacc, 0, 0, 0);
    if (node < N_NODES) {
#pragma unroll
      for (int r = 0; r < 16; r++) {
        if (acc[r] >= thr_r[r]) {
          int rl = (r & 3) + 8 * (r >> 2) + 4 * (lane >> 5);
          const float4* qp = (const float4*)&s_qf[rl * EMB_D];
          const float4* pj = (const float4*)(nrm + (size_t)node * EMB_D);
          float sim = dot16q(qp[0], qp[1], qp[2], qp[3], pj[0], pj[1], pj[2], pj[3]);
          unsigned long long key = ((unsigned long long)monokey(sim) << 32) |
                                   (unsigned long long)(0xFFFFFFFFu - (unsigned)node);
          int slot = atomicAdd(&s_cnt[rl], 1);
          if (slot < CAPM) s_ckey[rl][slot] = key;
        }
      }
    }
  }
  __syncthreads();

  // ---- Rank-by-count per row (wave w rows 4w..4w+3); fallback if overflow
  for (int q = 0; q < 4; q++) {
    int row = w * 4 + q;
    int grow = row0 + row;
    if (grow >= N_NODES) continue;
    int M = s_cnt[row];
    if (M <= CAPM) {   // M >= 20 guaranteed by threshold construction
      for (int c = lane; c < M; c += 64) {
        unsigned long long mykey = s_ckey[row][c];
        int rank = 0;
        for (int i = 0; i < M; i++) rank += (s_ckey[row][i] > mykey) ? 1 : 0;
        if (rank < K_TOP)
          topk[(size_t)grow * K_TOP + rank] =
              (int)(0xFFFFFFFFu - (unsigned)(mykey & 0xFFFFFFFFull));
      }
    } else {
      // Exact wave-local fallback: 20 argmax rounds, decreasing key cap.
      const float4* qp = (const float4*)&s_qf[row * EMB_D];
      float4 qa = qp[0], qb = qp[1], qc = qp[2], qd = qp[3];
      unsigned long long prev = ~0ull;
      for (int r = 0; r < K_TOP; r++) {
        unsigned long long best = 0ull;
        for (int j = lane; j < N_NODES; j += 64) {
          const float4* pj = (const float4*)(nrm + (size_t)j * EMB_D);
          float sim = dot16q(qa, qb, qc, qd, pj[0], pj[1], pj[2], pj[3]);
          unsigned long long key = ((unsigned long long)monokey(sim) << 32) |
                                   (unsigned long long)(0xFFFFFFFFu - (unsigned)j);
          if (key < prev && key > best) best = key;
        }
#pragma unroll
        for (int off = 32; off > 0; off >>= 1) {
          unsigned long long o = __shfl_down(best, off);
          if (o > best) best = o;
        }
        best = __shfl(best, 0);
        prev = best;
        if (lane == 0)
          topk[(size_t)grow * K_TOP + r] =
              (int)(0xFFFFFFFFu - (unsigned)(best & 0xFFFFFFFFull));
      }
    }
  }
}

// C[10000,256] = A[10000,128] @ B[128,256]. 16 rows/block, blockDim (256,2).
__global__ __launch_bounds__(512) void gemm1_kernel(
    const float* __restrict__ A, const float* __restrict__ B, float* __restrict__ Cc) {
  __shared__ float As[16][IN_DIM];
  int r0 = blockIdx.x * 16;
  int tid = threadIdx.y * 256 + threadIdx.x;
  {
    int rr = tid >> 5;
    int kk = tid & 31;
    ((float4*)&As[rr][0])[kk] = ((const float4*)(A + (size_t)(r0 + rr) * IN_DIM))[kk];
  }
  __syncthreads();
  int col = threadIdx.x;
  int y = threadIdx.y;
  float acc[8] = {0, 0, 0, 0, 0, 0, 0, 0};
#pragma unroll 4
  for (int k = 0; k < IN_DIM; k++) {
    float bv = B[(size_t)k * D1 + col];
#pragma unroll
    for (int r = 0; r < 8; r++) acc[r] = fmaf(As[y * 8 + r][k], bv, acc[r]);
  }
#pragma unroll
  for (int r = 0; r < 8; r++)
    Cc[(size_t)(r0 + y * 8 + r) * D1 + col] = acc[r];
}

// C[10000,64] = A[10000,256] @ B[256,64]. 16 rows/block, blockDim (64,4).
__global__ __launch_bounds__(256) void gemm2_kernel(
    const float* __restrict__ A, const float* __restrict__ B, float* __restrict__ Cc) {
  __shared__ float As[16][D1];
  int r0 = blockIdx.x * 16;
  int tid = threadIdx.y * 64 + threadIdx.x;
  for (int e = tid; e < 16 * (D1 / 4); e += 256) {
    int rr = e >> 6;
    int kk = e & 63;
    ((float4*)&As[rr][0])[kk] = ((const float4*)(A + (size_t)(r0 + rr) * D1))[kk];
  }
  __syncthreads();
  int col = threadIdx.x;
  int y = threadIdx.y;
  float acc[4] = {0, 0, 0, 0};
#pragma unroll 4
  for (int k = 0; k < D1; k++) {
    float bv = B[(size_t)k * CDIM + col];
#pragma unroll
    for (int r = 0; r < 4; r++) acc[r] = fmaf(As[y * 4 + r][k], bv, acc[r]);
  }
#pragma unroll
  for (int r = 0; r < 4; r++)
    Cc[(size_t)(r0 + y * 4 + r) * CDIM + col] = acc[r];
}

__global__ __launch_bounds__(256) void e1_kernel(
    const float* __restrict__ h1p, const float* __restrict__ a_src,
    const float* __restrict__ a_tgt, float* __restrict__ es, float* __restrict__ et) {
  int n = blockIdx.x;
  int tid = threadIdx.x;
  int w = tid >> 6, c = tid & 63;
  float hv = h1p[(size_t)n * D1 + tid];
  float ps = hv * a_src[tid];
  float pt = hv * a_tgt[tid];
#pragma unroll
  for (int off = 32; off > 0; off >>= 1) {
    ps += __shfl_down(ps, off);
    pt += __shfl_down(pt, off);
  }
  if (c == 0) {
    es[(size_t)n * H1 + w] = ps;
    et[(size_t)n * H1 + w] = pt;
  }
}

__global__ __launch_bounds__(256) void agg1_kernel(
    const float* __restrict__ h1p, const float* __restrict__ es,
    const float* __restrict__ et, const int* __restrict__ topk,
    const float* __restrict__ b1, float* __restrict__ h1o) {
  int i = blockIdx.x;
  int tid = threadIdx.x;
  __shared__ int nb[NEIGH];
  __shared__ float lg[NEIGH][H1];
  if (tid < K_TOP) nb[tid] = topk[(size_t)i * K_TOP + tid];
  else if (tid == K_TOP) nb[K_TOP] = i;
  __syncthreads();
  if (tid < NEIGH * H1) {
    int e = tid & 3, jj = tid >> 2;
    float L = es[(size_t)i * H1 + e] + et[(size_t)nb[jj] * H1 + e];
    lg[jj][e] = (L > 0.f) ? L : 0.2f * L;
  }
  __syncthreads();
  int h = tid >> 6;
  float m = -INFINITY;
#pragma unroll
  for (int jj = 0; jj < NEIGH; jj++) m = fmaxf(m, lg[jj][h]);
  float z = 0.f, acc = 0.f;
#pragma unroll
  for (int jj = 0; jj < NEIGH; jj++) {
    float w = expf(lg[jj][h] - m);
    z += w;
    acc = fmaf(w, h1p[(size_t)nb[jj] * D1 + tid], acc);
  }
  float o = acc / z + b1[tid];
  h1o[(size_t)i * D1 + tid] = fmaxf(o, 0.f);
}

__global__ __launch_bounds__(256) void e2_kernel(
    const float* __restrict__ h2p, const float* __restrict__ a_src,
    const float* __restrict__ a_tgt, float* __restrict__ es, float* __restrict__ et) {
  int tid = threadIdx.x;
  int n = blockIdx.x * 4 + (tid >> 6);
  int c = tid & 63;
  float hv = h2p[(size_t)n * CDIM + c];
  float ps = hv * a_src[c];
  float pt = hv * a_tgt[c];
#pragma unroll
  for (int off = 32; off > 0; off >>= 1) {
    ps += __shfl_down(ps, off);
    pt += __shfl_down(pt, off);
  }
  if (c == 0) { es[n] = ps; et[n] = pt; }
}

__global__ __launch_bounds__(256) void agg2_kernel(
    const float* __restrict__ h2p, const float* __restrict__ es,
    const float* __restrict__ et, const int* __restrict__ topk,
    const float* __restrict__ b2, float* __restrict__ out) {
  int tid = threadIdx.x;
  int li = tid >> 6;
  int c = tid & 63;
  int i = blockIdx.x * 4 + li;
  __shared__ int nb[4][NEIGH];
  __shared__ float lg[4][NEIGH];
  if (tid < 4 * NEIGH) {
    int li2 = tid / NEIGH, jj = tid % NEIGH;
    int node = blockIdx.x * 4 + li2;
    nb[li2][jj] = (jj < K_TOP) ? topk[(size_t)node * K_TOP + jj] : node;
  }
  __syncthreads();
  if (tid < 4 * NEIGH) {
    int li2 = tid / NEIGH, jj = tid % NEIGH;
    int node = blockIdx.x * 4 + li2;
    float L = es[node] + et[nb[li2][jj]];
    lg[li2][jj] = (L > 0.f) ? L : 0.2f * L;
  }
  __syncthreads();
  float m = -INFINITY;
#pragma unroll
  for (int jj = 0; jj < NEIGH; jj++) m = fmaxf(m, lg[li][jj]);
  float z = 0.f, acc = 0.f;
#pragma unroll
  for (int jj = 0; jj < NEIGH; jj++) {
    float w = expf(lg[li][jj] - m);
    z += w;
    acc = fmaf(w, h2p[(size_t)nb[li][jj] * CDIM + c], acc);
  }
  out[(size_t)i * CDIM + c] = acc / z + b2[c];
}

extern "C" void kernel_launch(void* const* d_in, const int* in_sizes, int n_in,
                              void* d_out, int out_size, void* d_ws, size_t ws_size,
                              hipStream_t stream) {
  const float* x   = (const float*)d_in[0];
  const float* emb = (const float*)d_in[1];
  const float* W1  = (const float*)d_in[2];
  const float* a1s = (const float*)d_in[3];
  const float* a1t = (const float*)d_in[4];
  const float* b1  = (const float*)d_in[5];
  const float* W2  = (const float*)d_in[6];
  const float* a2s = (const float*)d_in[7];
  const float* a2t = (const float*)d_in[8];
  const float* b2  = (const float*)d_in[9];
  float* out = (float*)d_out;

  size_t off = 0;
  auto alloc = [&](size_t bytes) {
    void* p = (char*)d_ws + off;
    off += (bytes + 255) & ~(size_t)255;
    return p;
  };
  float*          nrm  = (float*)alloc((size_t)N_NODES * EMB_D * sizeof(float));
  unsigned short* nrmh = (unsigned short*)alloc((size_t)N_NODES * EMB_D * sizeof(unsigned short));
  int*   topk = (int*)  alloc((size_t)N_NODES * K_TOP * sizeof(int));
  float* h1p  = (float*)alloc((size_t)N_NODES * D1 * sizeof(float));
  float* e1s  = (float*)alloc((size_t)N_NODES * H1 * sizeof(float));
  float* e1t  = (float*)alloc((size_t)N_NODES * H1 * sizeof(float));
  float* h1   = (float*)alloc((size_t)N_NODES * D1 * sizeof(float));
  float* h2p  = (float*)alloc((size_t)N_NODES * CDIM * sizeof(float));
  float* e2s  = (float*)alloc((size_t)N_NODES * sizeof(float));
  float* e2t  = (float*)alloc((size_t)N_NODES * sizeof(float));
  (void)ws_size; (void)in_sizes; (void)n_in; (void)out_size;

  normalize_kernel<<<(N_NODES + 255) / 256, 256, 0, stream>>>(emb, nrm, nrmh);
  sim_topk_kernel<<<NTILES, 512, 0, stream>>>(nrm, nrmh, topk);
  gemm1_kernel<<<N_NODES / 16, dim3(256, 2), 0, stream>>>(x, W1, h1p);
  e1_kernel<<<N_NODES, 256, 0, stream>>>(h1p, a1s, a1t, e1s, e1t);
  agg1_kernel<<<N_NODES, 256, 0, stream>>>(h1p, e1s, e1t, topk, b1, h1);
  gemm2_kernel<<<N_NODES / 16, dim3(64, 4), 0, stream>>>(h1, W2, h2p);
  e2_kernel<<<N_NODES / 4, 256, 0, stream>>>(h2p, a2s, a2t, e2s, e2t);
  agg2_kernel<<<N_NODES / 4, 256, 0, stream>>>(h2p, e2s, e2t, topk, b2, out);
}

// Round 6
// 181.525 us; speedup vs baseline: 1.9855x; 1.2134x over previous
//
#include <hip/hip_runtime.h>
#include <math.h>

// SpatialProcessor: 2-layer GAT over top-K cosine-sim graph. All f32.
// R5 -> R6: (a) threshold selection rewritten: fold 256 subset-maxima -> 64
// (disjointness kept), one 21-stage u32 bitonic sort in-wave, lane 44 = 20th
// largest (was: 20 rounds x 6-level u64 butterflies = dominant VALU cost).
// (b) MFMA passes unrolled x2 for memory-level parallelism. (c) e1/e2 score
// kernels fused into gemm1/gemm2 epilogues (bit-identical shfl trees).

#define N_NODES 10000
#define EMB_D   16
#define IN_DIM  128
#define H1      4
#define CDIM    64
#define D1      256   // 4*64
#define K_TOP   20
#define NEIGH   21    // K_TOP + self loop
#define SROWS   32    // rows per sim block
#define NTILES  313   // ceil(10000/32)
#define CAPM    64    // candidate capacity per row
#define GUARD   0.016f // 2 * bf16 dot error bound (2^-7)

typedef __attribute__((ext_vector_type(8)))  short short8;   // 8 bf16
typedef __attribute__((ext_vector_type(16))) float f32x16;

__device__ __forceinline__ unsigned monokey(float v) {
  unsigned u = __float_as_uint(v);
  return (u & 0x80000000u) ? ~u : (u | 0x80000000u);
}
__device__ __forceinline__ float invmono(unsigned m) {
  unsigned u = (m & 0x80000000u) ? (m ^ 0x80000000u) : ~m;
  return __uint_as_float(u);
}
__device__ __forceinline__ unsigned short f32_to_bf16(float f) {
  unsigned u = __float_as_uint(f);
  unsigned r = 0x7FFFu + ((u >> 16) & 1u);
  return (unsigned short)((u + r) >> 16);
}

// Fixed-order fmaf dot; MUST be bit-identical at every call site.
__device__ __forceinline__ float dot16q(float4 qa, float4 qb, float4 qc, float4 qd,
                                        float4 v0, float4 v1, float4 v2, float4 v3) {
  float a = 0.f;
  a = fmaf(qa.x, v0.x, a); a = fmaf(qa.y, v0.y, a);
  a = fmaf(qa.z, v0.z, a); a = fmaf(qa.w, v0.w, a);
  a = fmaf(qb.x, v1.x, a); a = fmaf(qb.y, v1.y, a);
  a = fmaf(qb.z, v1.z, a); a = fmaf(qb.w, v1.w, a);
  a = fmaf(qc.x, v2.x, a); a = fmaf(qc.y, v2.y, a);
  a = fmaf(qc.z, v2.z, a); a = fmaf(qc.w, v2.w, a);
  a = fmaf(qd.x, v3.x, a); a = fmaf(qd.y, v3.y, a);
  a = fmaf(qd.z, v3.z, a); a = fmaf(qd.w, v3.w, a);
  return a;
}

__global__ __launch_bounds__(256) void normalize_kernel(
    const float* __restrict__ emb, float* __restrict__ nrm,
    unsigned short* __restrict__ nrmh) {
  int i = blockIdx.x * 256 + threadIdx.x;
  if (i >= N_NODES) return;
  const float4* p = (const float4*)(emb + (size_t)i * EMB_D);
  float4 v[4];
  float ss = 0.f;
#pragma unroll
  for (int k = 0; k < 4; k++) {
    v[k] = p[k];
    ss = fmaf(v[k].x, v[k].x, ss);
    ss = fmaf(v[k].y, v[k].y, ss);
    ss = fmaf(v[k].z, v[k].z, ss);
    ss = fmaf(v[k].w, v[k].w, ss);
  }
  float nv = sqrtf(ss);
  float4* o = (float4*)(nrm + (size_t)i * EMB_D);
  ushort4* oh = (ushort4*)(nrmh + (size_t)i * EMB_D);
#pragma unroll
  for (int k = 0; k < 4; k++) {
    float4 t;
    t.x = v[k].x / nv; t.y = v[k].y / nv; t.z = v[k].z / nv; t.w = v[k].w / nv;
    o[k] = t;
    ushort4 h;
    h.x = f32_to_bf16(t.x); h.y = f32_to_bf16(t.y);
    h.z = f32_to_bf16(t.z); h.w = f32_to_bf16(t.w);
    oh[k] = h;
  }
}

// 32 rows per 512-thread block (8 waves split the 313 j-tiles); grid 313.
__global__ __launch_bounds__(512) void sim_topk_kernel(
    const float* __restrict__ nrm, const unsigned short* __restrict__ nrmh,
    int* __restrict__ topk) {
  __shared__ unsigned short s_qbf[SROWS * EMB_D];        // 1 KB
  __shared__ float s_qf[SROWS * EMB_D];                  // 2 KB
  __shared__ float s_smax[SROWS][256];                   // 32 KB
  __shared__ float s_thr[SROWS];
  __shared__ unsigned long long s_ckey[SROWS][CAPM];     // 16 KB
  __shared__ int s_cnt[SROWS];

  int tid = threadIdx.x;
  int w = tid >> 6, lane = tid & 63;
  int lo5 = lane & 31, hi = lane >> 5;
  int row0 = blockIdx.x * SROWS;

  if (tid < SROWS * EMB_D) {
    int gi = row0 * EMB_D + tid;
    float v = (gi < N_NODES * EMB_D) ? nrm[gi] : 0.f;
    s_qf[tid] = v;
    s_qbf[tid] = f32_to_bf16(v);
  }
  if (tid < SROWS) s_cnt[tid] = 0;
  __syncthreads();

  // A-frag (identical across waves): lane -> row lo5, dims hi*8..hi*8+7
  short8 afrag = *(const short8*)&s_qbf[lo5 * EMB_D + hi * 8];
  const f32x16 zacc = (f32x16)0.0f;

  // ---- Pass 1: MFMA approx sims; per-lane per-reg running max (unroll x2) --
  float rm[16];
#pragma unroll
  for (int r = 0; r < 16; r++) rm[r] = -INFINITY;

  for (int t = w; t < NTILES; t += 16) {
    int nodeA = t * 32 + lo5;
    int t2 = t + 8;
    int nodeB = t2 * 32 + lo5;
    short8 bA = (short8)(short)0, bB = (short8)(short)0;
    if (nodeA < N_NODES) bA = *(const short8*)&nrmh[(size_t)nodeA * EMB_D + hi * 8];
    if (t2 < NTILES && nodeB < N_NODES)
      bB = *(const short8*)&nrmh[(size_t)nodeB * EMB_D + hi * 8];
    f32x16 accA = __builtin_amdgcn_mfma_f32_32x32x16_bf16(afrag, bA, zacc, 0, 0, 0);
    if (nodeA < N_NODES) {
#pragma unroll
      for (int r = 0; r < 16; r++) rm[r] = fmaxf(rm[r], accA[r]);
    }
    if (t2 < NTILES) {
      f32x16 accB = __builtin_amdgcn_mfma_f32_32x32x16_bf16(afrag, bB, zacc, 0, 0, 0);
      if (nodeB < N_NODES) {
#pragma unroll
        for (int r = 0; r < 16; r++) rm[r] = fmaxf(rm[r], accB[r]);
      }
    }
  }
#pragma unroll
  for (int r = 0; r < 16; r++) {
    int rl = (r & 3) + 8 * (r >> 2) + 4 * hi;   // C-layout row
    s_smax[rl][w * 32 + lo5] = rm[r];
  }
  __syncthreads();

  // ---- Threshold: wave w rows 4w..4w+3. Fold 256 -> 64 subset maxima
  // (unions of disjoint subsets stay disjoint), 21-stage u32 bitonic sort,
  // lane 44 = 20th largest. ----
  for (int q = 0; q < 4; q++) {
    int row = w * 4 + q;
    float m01 = fmaxf(s_smax[row][lane], s_smax[row][64 + lane]);
    float m23 = fmaxf(s_smax[row][128 + lane], s_smax[row][192 + lane]);
    unsigned v = monokey(fmaxf(m01, m23));
#pragma unroll
    for (int k = 2; k <= 64; k <<= 1) {
#pragma unroll
      for (int j = k >> 1; j > 0; j >>= 1) {
        unsigned o = __shfl_xor(v, j);
        bool upper = (lane & j) != 0;
        bool ascend = (lane & k) == 0;
        unsigned mx = v > o ? v : o;
        unsigned mn = v > o ? o : v;
        v = (upper == ascend) ? mx : mn;   // ascending overall: lane63 = max
      }
    }
    unsigned t20 = __shfl(v, 44);          // 20th largest of 64
    if (lane == 0)
      s_thr[row] = (row0 + row < N_NODES) ? invmono(t20) - GUARD : INFINITY;
  }
  __syncthreads();

  // Hoist per-(lane,reg) thresholds into registers.
  float thr_r[16];
#pragma unroll
  for (int r = 0; r < 16; r++)
    thr_r[r] = s_thr[(r & 3) + 8 * (r >> 2) + 4 * hi];

  // ---- Pass 2: MFMA rescan; candidates get exact f32 dot + key append ----
  for (int t = w; t < NTILES; t += 16) {
#pragma unroll
    for (int u = 0; u < 2; u++) {
      int tt = t + u * 8;
      if (tt >= NTILES) break;
      int node = tt * 32 + lo5;
      short8 bfrag = (short8)(short)0;
      if (node < N_NODES)
        bfrag = *(const short8*)&nrmh[(size_t)node * EMB_D + hi * 8];
      f32x16 acc = __builtin_amdgcn_mfma_f32_32x32x16_bf16(afrag, bfrag, zacc, 0, 0, 0);
      if (node < N_NODES) {
#pragma unroll
        for (int r = 0; r < 16; r++) {
          if (acc[r] >= thr_r[r]) {
            int rl = (r & 3) + 8 * (r >> 2) + 4 * hi;
            const float4* qp = (const float4*)&s_qf[rl * EMB_D];
            const float4* pj = (const float4*)(nrm + (size_t)node * EMB_D);
            float sim = dot16q(qp[0], qp[1], qp[2], qp[3], pj[0], pj[1], pj[2], pj[3]);
            unsigned long long key = ((unsigned long long)monokey(sim) << 32) |
                                     (unsigned long long)(0xFFFFFFFFu - (unsigned)node);
            int slot = atomicAdd(&s_cnt[rl], 1);
            if (slot < CAPM) s_ckey[rl][slot] = key;
          }
        }
      }
    }
  }
  __syncthreads();

  // ---- Rank-by-count per row (wave w rows 4w..4w+3); fallback if overflow
  for (int q = 0; q < 4; q++) {
    int row = w * 4 + q;
    int grow = row0 + row;
    if (grow >= N_NODES) continue;
    int M = s_cnt[row];
    if (M <= CAPM) {   // M >= 20 guaranteed by threshold construction
      if (lane < M) {
        unsigned long long mykey = s_ckey[row][lane];
        int rank = 0;
        for (int i = 0; i < M; i++) rank += (s_ckey[row][i] > mykey) ? 1 : 0;
        if (rank < K_TOP)
          topk[(size_t)grow * K_TOP + rank] =
              (int)(0xFFFFFFFFu - (unsigned)(mykey & 0xFFFFFFFFull));
      }
    } else {
      // Exact wave-local fallback: 20 argmax rounds, decreasing key cap.
      const float4* qp = (const float4*)&s_qf[row * EMB_D];
      float4 qa = qp[0], qb = qp[1], qc = qp[2], qd = qp[3];
      unsigned long long prev = ~0ull;
      for (int r = 0; r < K_TOP; r++) {
        unsigned long long best = 0ull;
        for (int j = lane; j < N_NODES; j += 64) {
          const float4* pj = (const float4*)(nrm + (size_t)j * EMB_D);
          float sim = dot16q(qa, qb, qc, qd, pj[0], pj[1], pj[2], pj[3]);
          unsigned long long key = ((unsigned long long)monokey(sim) << 32) |
                                   (unsigned long long)(0xFFFFFFFFu - (unsigned)j);
          if (key < prev && key > best) best = key;
        }
#pragma unroll
        for (int off = 32; off > 0; off >>= 1) {
          unsigned long long o = __shfl_down(best, off);
          if (o > best) best = o;
        }
        best = __shfl(best, 0);
        prev = best;
        if (lane == 0)
          topk[(size_t)grow * K_TOP + r] =
              (int)(0xFFFFFFFFu - (unsigned)(best & 0xFFFFFFFFull));
      }
    }
  }
}

// C[10000,256] = A[10000,128] @ B[128,256], fused e1 scores.
// blockDim (256,2); each wave = 64 consecutive cols of one y => one head.
__global__ __launch_bounds__(512) void gemm1_kernel(
    const float* __restrict__ A, const float* __restrict__ B,
    const float* __restrict__ a_src, const float* __restrict__ a_tgt,
    float* __restrict__ Cc, float* __restrict__ es, float* __restrict__ et) {
  __shared__ float As[16][IN_DIM];
  int r0 = blockIdx.x * 16;
  int tid = threadIdx.y * 256 + threadIdx.x;
  {
    int rr = tid >> 5;
    int kk = tid & 31;
    ((float4*)&As[rr][0])[kk] = ((const float4*)(A + (size_t)(r0 + rr) * IN_DIM))[kk];
  }
  __syncthreads();
  int col = threadIdx.x;
  int y = threadIdx.y;
  float acc[8] = {0, 0, 0, 0, 0, 0, 0, 0};
#pragma unroll 4
  for (int k = 0; k < IN_DIM; k++) {
    float bv = B[(size_t)k * D1 + col];
#pragma unroll
    for (int r = 0; r < 8; r++) acc[r] = fmaf(As[y * 8 + r][k], bv, acc[r]);
  }
#pragma unroll
  for (int r = 0; r < 8; r++)
    Cc[(size_t)(r0 + y * 8 + r) * D1 + col] = acc[r];
  // Fused e1: head h = col>>6 (constant per wave); reduce over 64 lanes.
  float as = a_src[col], at = a_tgt[col];
  int h = col >> 6;
#pragma unroll
  for (int r = 0; r < 8; r++) {
    float ps = acc[r] * as, pt = acc[r] * at;
#pragma unroll
    for (int off = 32; off > 0; off >>= 1) {
      ps += __shfl_down(ps, off);
      pt += __shfl_down(pt, off);
    }
    if ((col & 63) == 0) {
      es[(size_t)(r0 + y * 8 + r) * H1 + h] = ps;
      et[(size_t)(r0 + y * 8 + r) * H1 + h] = pt;
    }
  }
}

// C[10000,64] = A[10000,256] @ B[256,64], fused e2 scores.
// blockDim (64,4); each wave = the 64 cols of one y.
__global__ __launch_bounds__(256) void gemm2_kernel(
    const float* __restrict__ A, const float* __restrict__ B,
    const float* __restrict__ a_src, const float* __restrict__ a_tgt,
    float* __restrict__ Cc, float* __restrict__ es, float* __restrict__ et) {
  __shared__ float As[16][D1];
  int r0 = blockIdx.x * 16;
  int tid = threadIdx.y * 64 + threadIdx.x;
  for (int e = tid; e < 16 * (D1 / 4); e += 256) {
    int rr = e >> 6;
    int kk = e & 63;
    ((float4*)&As[rr][0])[kk] = ((const float4*)(A + (size_t)(r0 + rr) * D1))[kk];
  }
  __syncthreads();
  int col = threadIdx.x;
  int y = threadIdx.y;
  float acc[4] = {0, 0, 0, 0};
#pragma unroll 4
  for (int k = 0; k < D1; k++) {
    float bv = B[(size_t)k * CDIM + col];
#pragma unroll
    for (int r = 0; r < 4; r++) acc[r] = fmaf(As[y * 4 + r][k], bv, acc[r]);
  }
#pragma unroll
  for (int r = 0; r < 4; r++)
    Cc[(size_t)(r0 + y * 4 + r) * CDIM + col] = acc[r];
  float as = a_src[col], at = a_tgt[col];
#pragma unroll
  for (int r = 0; r < 4; r++) {
    float ps = acc[r] * as, pt = acc[r] * at;
#pragma unroll
    for (int off = 32; off > 0; off >>= 1) {
      ps += __shfl_down(ps, off);
      pt += __shfl_down(pt, off);
    }
    if (col == 0) {
      es[r0 + y * 4 + r] = ps;
      et[r0 + y * 4 + r] = pt;
    }
  }
}

__global__ __launch_bounds__(256) void agg1_kernel(
    const float* __restrict__ h1p, const float* __restrict__ es,
    const float* __restrict__ et, const int* __restrict__ topk,
    const float* __restrict__ b1, float* __restrict__ h1o) {
  int i = blockIdx.x;
  int tid = threadIdx.x;
  __shared__ int nb[NEIGH];
  __shared__ float lg[NEIGH][H1];
  if (tid < K_TOP) nb[tid] = topk[(size_t)i * K_TOP + tid];
  else if (tid == K_TOP) nb[K_TOP] = i;
  __syncthreads();
  if (tid < NEIGH * H1) {
    int e = tid & 3, jj = tid >> 2;
    float L = es[(size_t)i * H1 + e] + et[(size_t)nb[jj] * H1 + e];
    lg[jj][e] = (L > 0.f) ? L : 0.2f * L;
  }
  __syncthreads();
  int h = tid >> 6;
  float m = -INFINITY;
#pragma unroll
  for (int jj = 0; jj < NEIGH; jj++) m = fmaxf(m, lg[jj][h]);
  float z = 0.f, acc = 0.f;
#pragma unroll
  for (int jj = 0; jj < NEIGH; jj++) {
    float w = expf(lg[jj][h] - m);
    z += w;
    acc = fmaf(w, h1p[(size_t)nb[jj] * D1 + tid], acc);
  }
  float o = acc / z + b1[tid];
  h1o[(size_t)i * D1 + tid] = fmaxf(o, 0.f);
}

__global__ __launch_bounds__(256) void agg2_kernel(
    const float* __restrict__ h2p, const float* __restrict__ es,
    const float* __restrict__ et, const int* __restrict__ topk,
    const float* __restrict__ b2, float* __restrict__ out) {
  int tid = threadIdx.x;
  int li = tid >> 6;
  int c = tid & 63;
  int i = blockIdx.x * 4 + li;
  __shared__ int nb[4][NEIGH];
  __shared__ float lg[4][NEIGH];
  if (tid < 4 * NEIGH) {
    int li2 = tid / NEIGH, jj = tid % NEIGH;
    int node = blockIdx.x * 4 + li2;
    nb[li2][jj] = (jj < K_TOP) ? topk[(size_t)node * K_TOP + jj] : node;
  }
  __syncthreads();
  if (tid < 4 * NEIGH) {
    int li2 = tid / NEIGH, jj = tid % NEIGH;
    int node = blockIdx.x * 4 + li2;
    float L = es[node] + et[nb[li2][jj]];
    lg[li2][jj] = (L > 0.f) ? L : 0.2f * L;
  }
  __syncthreads();
  float m = -INFINITY;
#pragma unroll
  for (int jj = 0; jj < NEIGH; jj++) m = fmaxf(m, lg[li][jj]);
  float z = 0.f, acc = 0.f;
#pragma unroll
  for (int jj = 0; jj < NEIGH; jj++) {
    float w = expf(lg[li][jj] - m);
    z += w;
    acc = fmaf(w, h2p[(size_t)nb[li][jj] * CDIM + c], acc);
  }
  out[(size_t)i * CDIM + c] = acc / z + b2[c];
}

extern "C" void kernel_launch(void* const* d_in, const int* in_sizes, int n_in,
                              void* d_out, int out_size, void* d_ws, size_t ws_size,
                              hipStream_t stream) {
  const float* x   = (const float*)d_in[0];
  const float* emb = (const float*)d_in[1];
  const float* W1  = (const float*)d_in[2];
  const float* a1s = (const float*)d_in[3];
  const float* a1t = (const float*)d_in[4];
  const float* b1  = (const float*)d_in[5];
  const float* W2  = (const float*)d_in[6];
  const float* a2s = (const float*)d_in[7];
  const float* a2t = (const float*)d_in[8];
  const float* b2  = (const float*)d_in[9];
  float* out = (float*)d_out;

  size_t off = 0;
  auto alloc = [&](size_t bytes) {
    void* p = (char*)d_ws + off;
    off += (bytes + 255) & ~(size_t)255;
    return p;
  };
  float*          nrm  = (float*)alloc((size_t)N_NODES * EMB_D * sizeof(float));
  unsigned short* nrmh = (unsigned short*)alloc((size_t)N_NODES * EMB_D * sizeof(unsigned short));
  int*   topk = (int*)  alloc((size_t)N_NODES * K_TOP * sizeof(int));
  float* h1p  = (float*)alloc((size_t)N_NODES * D1 * sizeof(float));
  float* e1s  = (float*)alloc((size_t)N_NODES * H1 * sizeof(float));
  float* e1t  = (float*)alloc((size_t)N_NODES * H1 * sizeof(float));
  float* h1   = (float*)alloc((size_t)N_NODES * D1 * sizeof(float));
  float* h2p  = (float*)alloc((size_t)N_NODES * CDIM * sizeof(float));
  float* e2s  = (float*)alloc((size_t)N_NODES * sizeof(float));
  float* e2t  = (float*)alloc((size_t)N_NODES * sizeof(float));
  (void)ws_size; (void)in_sizes; (void)n_in; (void)out_size;

  normalize_kernel<<<(N_NODES + 255) / 256, 256, 0, stream>>>(emb, nrm, nrmh);
  sim_topk_kernel<<<NTILES, 512, 0, stream>>>(nrm, nrmh, topk);
  gemm1_kernel<<<N_NODES / 16, dim3(256, 2), 0, stream>>>(x, W1, a1s, a1t, h1p, e1s, e1t);
  agg1_kernel<<<N_NODES, 256, 0, stream>>>(h1p, e1s, e1t, topk, b1, h1);
  gemm2_kernel<<<N_NODES / 16, dim3(64, 4), 0, stream>>>(h1, W2, a2s, a2t, h2p, e2s, e2t);
  agg2_kernel<<<N_NODES / 4, 256, 0, stream>>>(h2p, e2s, e2t, topk, b2, out);
}